// Round 3
// baseline (4010.533 us; speedup 1.0000x reference)
//
#include <hip/hip_runtime.h>
#include <hip/hip_bf16.h>
#include <stdint.h>

#define GRIDN 48
#define F 2304
#define C 128
#define H 8
#define DH 16
#define NB 2          // batch (meshes)
#define WID 256
#define NLV 49        // BFS levels for GRID=48, anchor at (24,24)

typedef __hip_bfloat16 bf16;

__device__ __forceinline__ float b2f(bf16 v) { return __bfloat162float(v); }

// ---------------------------------------------------------------- K-1: input dtype detector
// Interpret x's first 2048 entries as bf16. True-bf16 N(0,1) data: |v| <= ~6.
// fp32 data read as bf16 exposes random mantissa halves -> some |v|>1e10 or NaN
// with probability ~1. flag=1 -> inputs are fp32; flag=0 -> inputs are bf16.
__global__ void k_detect(const void* __restrict__ x, int* __restrict__ flag) {
    __shared__ int bad;
    if (threadIdx.x == 0) bad = 0;
    __syncthreads();
    const bf16* xb = (const bf16*)x;
    int insane = 0;
    #pragma unroll
    for (int i = 0; i < 8; ++i) {
        float v = b2f(xb[threadIdx.x * 8 + i]);
        if (!(fabsf(v) < 1e10f)) insane = 1;   // catches NaN/Inf/huge
    }
    if (insane) atomicOr(&bad, 1);
    __syncthreads();
    if (threadIdx.x == 0) *flag = bad;
}

// ---------------------------------------------------------------- K0: level-of-face
__global__ void k_lvof(int* __restrict__ lvOf) {
    int f = blockIdx.x * blockDim.x + threadIdx.x;
    if (f < F) {
        int i = f / GRIDN, j = f % GRIDN, c = GRIDN / 2;
        lvOf[f] = abs(i - c) + abs(j - c);
    }
}

// ---------------------------------------------------------------- K0b: convert all weights/biases to fp32
struct WSeg { const void* src; int off; int cnt; };
struct WSegs { WSeg s[14]; };

__global__ void k_convert(WSegs segs, const int* __restrict__ flag,
                          float* __restrict__ dst, int total) {
    int i = blockIdx.x * blockDim.x + threadIdx.x;
    if (i >= total) return;
    bool f32 = (*flag != 0);
    #pragma unroll 1
    for (int j = 0; j < 14; ++j) {
        int off = segs.s[j].off, cnt = segs.s[j].cnt;
        if (i >= off && i < off + cnt) {
            int k = i - off;
            dst[i] = f32 ? ((const float*)segs.s[j].src)[k]
                         : b2f(((const bf16*)segs.s[j].src)[k]);
            return;
        }
    }
}

// ---------------------------------------------------------------- K1: x[B,C,F] -> cur[B,F,C] f32 (dtype-flag branch)
__global__ void k_transpose_in(const void* __restrict__ x, const int* __restrict__ flag,
                               float* __restrict__ cur) {
    __shared__ float tile[32][33];
    bool f32 = (*flag != 0);
    int b = blockIdx.z;
    int f0 = blockIdx.x * 32, c0 = blockIdx.y * 32;
    int tx = threadIdx.x, ty = threadIdx.y;            // 32 x 8
    #pragma unroll
    for (int i = 0; i < 4; ++i) {
        int c = c0 + ty + i * 8;
        size_t idx = ((size_t)b * C + c) * F + f0 + tx;
        tile[ty + i * 8][tx] = f32 ? ((const float*)x)[idx] : b2f(((const bf16*)x)[idx]);
    }
    __syncthreads();
    #pragma unroll
    for (int i = 0; i < 4; ++i) {
        int f = f0 + ty + i * 8;
        cur[((size_t)b * F + f) * C + c0 + tx] = tile[tx][ty + i * 8];
    }
}

// ---------------------------------------------------------------- K2: qh/kh/vh init GEMMs (8 rows/block, 128 thr)
__global__ __launch_bounds__(128) void k_proj_init(
        const float* __restrict__ cur,
        const float* __restrict__ Wq, const float* __restrict__ Wk, const float* __restrict__ Wv,
        float* __restrict__ qh, float* __restrict__ kh, float* __restrict__ vh,
        float* __restrict__ kh0, float* __restrict__ vh0) {
    __shared__ float rows[8][C];
    int r0 = blockIdx.x * 8;
    int tid = threadIdx.x;  // 0..127
    #pragma unroll
    for (int r = 0; r < 8; ++r) rows[r][tid] = cur[(size_t)(r0 + r) * C + tid];
    __syncthreads();
    float aq[8], ak[8], av[8];
    #pragma unroll
    for (int r = 0; r < 8; ++r) { aq[r] = 0.f; ak[r] = 0.f; av[r] = 0.f; }
    for (int k = 0; k < C; ++k) {
        float wq = Wq[k * C + tid];
        float wk = Wk[k * C + tid];
        float wv = Wv[k * C + tid];
        #pragma unroll
        for (int r = 0; r < 8; ++r) {
            float xv = rows[r][k];
            aq[r] = fmaf(xv, wq, aq[r]);
            ak[r] = fmaf(xv, wk, ak[r]);
            av[r] = fmaf(xv, wv, av[r]);
        }
    }
    const float scale = 0.25f;  // 1/sqrt(DH)
    #pragma unroll
    for (int r = 0; r < 8; ++r) {
        size_t o = (size_t)(r0 + r) * C + tid;
        qh[o] = aq[r] * scale;
        kh[o] = ak[r]; kh0[o] = ak[r];
        vh[o] = av[r]; vh0[o] = av[r];
    }
}

// ---------------------------------------------------------------- K3: one BFS level (one block per active query)
__global__ __launch_bounds__(256) void k_level(
        int lv, int Bd,
        const int* __restrict__ levels, const int* __restrict__ lvOf,
        const float* __restrict__ qh_all, float* __restrict__ cur,
        float* __restrict__ kh, float* __restrict__ vh,
        const float* __restrict__ kh0, const float* __restrict__ vh0,
        const float* __restrict__ Wk, const float* __restrict__ Wv, const float* __restrict__ Wo) {
    int bx = blockIdx.x;
    int mesh = (bx >> 2) & 1;
    int slot = (bx >> 3) * 4 + (bx & 3);
    if (slot >= Bd) return;                       // block-uniform
    int face = levels[lv * Bd + slot];
    if (face >= F || face < 0) return;            // pad slot (dropped in ref)

    __shared__ float sQ[C], sQh[C], sAcc[C], sL[H], sP[C], sNew[C];
    int tid = threadIdx.x;
    size_t row = ((size_t)mesh * F + face) * C;
    if (tid < C) { sQ[tid] = cur[row + tid]; sQh[tid] = qh_all[row + tid]; }
    __syncthreads();

    int head = tid >> 5, sub = tid & 31;
    float q[DH];
    #pragma unroll
    for (int d = 0; d < DH; ++d) q[d] = sQh[head * DH + d];

    const size_t mbase = (size_t)mesh * F * C + head * DH;
    const float* kb  = kh  + mbase;
    const float* vb  = vh  + mbase;
    const float* kb0 = kh0 + mbase;
    const float* vb0 = vh0 + mbase;

    float m = -1e30f, l = 0.f;
    float acc[DH];
    #pragma unroll
    for (int d = 0; d < DH; ++d) acc[d] = 0.f;

    // F % 32 == 0: every lane does exactly F/32 iterations
    for (int k = sub; k < F; k += 32) {
        bool stale = (lvOf[k] == lv);             // ring-lv keys: use frozen initial K/V
        const float* kr = (stale ? kb0 : kb) + (size_t)k * C;
        const float* vr = (stale ? vb0 : vb) + (size_t)k * C;
        float4 k0 = *(const float4*)kr;
        float4 k1 = *(const float4*)(kr + 4);
        float4 k2 = *(const float4*)(kr + 8);
        float4 k3 = *(const float4*)(kr + 12);
        float s = q[0] * k0.x;
        s = fmaf(q[1], k0.y, s);  s = fmaf(q[2], k0.z, s);  s = fmaf(q[3], k0.w, s);
        s = fmaf(q[4], k1.x, s);  s = fmaf(q[5], k1.y, s);  s = fmaf(q[6], k1.z, s);  s = fmaf(q[7], k1.w, s);
        s = fmaf(q[8], k2.x, s);  s = fmaf(q[9], k2.y, s);  s = fmaf(q[10], k2.z, s); s = fmaf(q[11], k2.w, s);
        s = fmaf(q[12], k3.x, s); s = fmaf(q[13], k3.y, s); s = fmaf(q[14], k3.z, s); s = fmaf(q[15], k3.w, s);
        float4 v0 = *(const float4*)vr;
        float4 v1 = *(const float4*)(vr + 4);
        float4 v2 = *(const float4*)(vr + 8);
        float4 v3 = *(const float4*)(vr + 12);
        float mn = fmaxf(m, s);
        float c1 = __expf(m - mn);
        float p  = __expf(s - mn);
        l = l * c1 + p;
        acc[0]  = fmaf(acc[0],  c1, p * v0.x);  acc[1]  = fmaf(acc[1],  c1, p * v0.y);
        acc[2]  = fmaf(acc[2],  c1, p * v0.z);  acc[3]  = fmaf(acc[3],  c1, p * v0.w);
        acc[4]  = fmaf(acc[4],  c1, p * v1.x);  acc[5]  = fmaf(acc[5],  c1, p * v1.y);
        acc[6]  = fmaf(acc[6],  c1, p * v1.z);  acc[7]  = fmaf(acc[7],  c1, p * v1.w);
        acc[8]  = fmaf(acc[8],  c1, p * v2.x);  acc[9]  = fmaf(acc[9],  c1, p * v2.y);
        acc[10] = fmaf(acc[10], c1, p * v2.z);  acc[11] = fmaf(acc[11], c1, p * v2.w);
        acc[12] = fmaf(acc[12], c1, p * v3.x);  acc[13] = fmaf(acc[13], c1, p * v3.y);
        acc[14] = fmaf(acc[14], c1, p * v3.z);  acc[15] = fmaf(acc[15], c1, p * v3.w);
        m = mn;
    }

    // merge 32 per-lane online-softmax states per head (xor<32 stays within half-wave)
    #pragma unroll
    for (int w = 16; w >= 1; w >>= 1) {
        float mo = __shfl_xor(m, w);
        float lo = __shfl_xor(l, w);
        float mn = fmaxf(m, mo);
        float c1 = __expf(m - mn), c2 = __expf(mo - mn);
        l = l * c1 + lo * c2;
        #pragma unroll
        for (int d = 0; d < DH; ++d) {
            float ao = __shfl_xor(acc[d], w);
            acc[d] = acc[d] * c1 + ao * c2;
        }
        m = mn;
    }
    if (sub == 0) {
        sL[head] = l;
        #pragma unroll
        for (int d = 0; d < DH; ++d) sAcc[head * DH + d] = acc[d];
    }
    __syncthreads();
    if (tid < C) sP[tid] = sAcc[tid] / sL[tid >> 4];
    __syncthreads();
    if (tid < C) {
        float a = 0.f;
        for (int k = 0; k < C; ++k) a = fmaf(sP[k], Wo[k * C + tid], a);
        float nv = sQ[tid] + a;                  // resid
        sNew[tid] = nv;
        cur[row + tid] = nv;                     // only this block touches this row
    }
    __syncthreads();
    // eager K/V row update; same-level readers use kh0/vh0 for this row -> benign race
    if (tid < C) {
        float a = 0.f;
        for (int k = 0; k < C; ++k) a = fmaf(sNew[k], Wk[k * C + tid], a);
        kh[row + tid] = a;
    } else {
        int c = tid - C;
        float a = 0.f;
        for (int k = 0; k < C; ++k) a = fmaf(sNew[k], Wv[k * C + c], a);
        vh[row + c] = a;
    }
}

// ---------------------------------------------------------------- K4: 5-layer MLP + sigmoid (8 rows/block), fp32 out
__global__ __launch_bounds__(256) void k_mlp(
        const float* __restrict__ cur,
        const float* __restrict__ W1, const float* __restrict__ b1,
        const float* __restrict__ W2, const float* __restrict__ b2,
        const float* __restrict__ W3, const float* __restrict__ b3,
        const float* __restrict__ W4, const float* __restrict__ b4,
        const float* __restrict__ W5, const float* __restrict__ b5,
        float* __restrict__ out_scores) {
    __shared__ float sIn[8][C];
    __shared__ float sA[8][WID];
    __shared__ float sB[8][WID];
    int tid = threadIdx.x;                        // 0..255
    int r0 = blockIdx.x * 8;
    for (int i = tid; i < 8 * C; i += 256) sIn[i >> 7][i & 127] = cur[(size_t)r0 * C + i];
    __syncthreads();
    { // L1: C -> WID
        float a[8];
        #pragma unroll
        for (int r = 0; r < 8; ++r) a[r] = 0.f;
        for (int k = 0; k < C; ++k) {
            float w = W1[k * WID + tid];
            #pragma unroll
            for (int r = 0; r < 8; ++r) a[r] = fmaf(sIn[r][k], w, a[r]);
        }
        float bias = b1[tid];
        #pragma unroll
        for (int r = 0; r < 8; ++r) sA[r][tid] = fmaxf(a[r] + bias, 0.f);
    }
    __syncthreads();
    { // L2
        float a[8];
        #pragma unroll
        for (int r = 0; r < 8; ++r) a[r] = 0.f;
        for (int k = 0; k < WID; ++k) {
            float w = W2[k * WID + tid];
            #pragma unroll
            for (int r = 0; r < 8; ++r) a[r] = fmaf(sA[r][k], w, a[r]);
        }
        float bias = b2[tid];
        #pragma unroll
        for (int r = 0; r < 8; ++r) sB[r][tid] = fmaxf(a[r] + bias, 0.f);
    }
    __syncthreads();
    { // L3
        float a[8];
        #pragma unroll
        for (int r = 0; r < 8; ++r) a[r] = 0.f;
        for (int k = 0; k < WID; ++k) {
            float w = W3[k * WID + tid];
            #pragma unroll
            for (int r = 0; r < 8; ++r) a[r] = fmaf(sB[r][k], w, a[r]);
        }
        float bias = b3[tid];
        #pragma unroll
        for (int r = 0; r < 8; ++r) sA[r][tid] = fmaxf(a[r] + bias, 0.f);
    }
    __syncthreads();
    { // L4
        float a[8];
        #pragma unroll
        for (int r = 0; r < 8; ++r) a[r] = 0.f;
        for (int k = 0; k < WID; ++k) {
            float w = W4[k * WID + tid];
            #pragma unroll
            for (int r = 0; r < 8; ++r) a[r] = fmaf(sA[r][k], w, a[r]);
        }
        float bias = b4[tid];
        #pragma unroll
        for (int r = 0; r < 8; ++r) sB[r][tid] = fmaxf(a[r] + bias, 0.f);
    }
    __syncthreads();
    if (tid < 8) { // L5 + sigmoid
        float a = b5[0];
        for (int k = 0; k < WID; ++k) a = fmaf(sB[tid][k], W5[k], a);
        out_scores[r0 + tid] = 1.f / (1.f + __expf(-a));
    }
}

// ---------------------------------------------------------------- K5: cur[B,F,C] f32 -> out0[B,C,F] f32
__global__ void k_transpose_out(const float* __restrict__ cur, float* __restrict__ out) {
    __shared__ float tile[32][33];
    int b = blockIdx.z;
    int f0 = blockIdx.x * 32, c0 = blockIdx.y * 32;
    int tx = threadIdx.x, ty = threadIdx.y;
    #pragma unroll
    for (int i = 0; i < 4; ++i) {
        int f = f0 + ty + i * 8;
        tile[ty + i * 8][tx] = cur[((size_t)b * F + f) * C + c0 + tx];
    }
    __syncthreads();
    #pragma unroll
    for (int i = 0; i < 4; ++i) {
        int c = c0 + ty + i * 8;
        out[((size_t)b * C + c) * F + f0 + tx] = tile[tx][ty + i * 8];
    }
}

// ----------------------------------------------------------------
extern "C" void kernel_launch(void* const* d_in, const int* in_sizes, int n_in,
                              void* d_out, int out_size, void* d_ws, size_t ws_size,
                              hipStream_t stream) {
    const int* levels = (const int*)d_in[15];
    int Bd = in_sizes[15] / NLV;                  // ring capacity per level

    const size_t n = (size_t)NB * F * C;          // 589824
    float* cur = (float*)d_ws;
    float* qh  = cur + n;
    float* kh  = qh + n;
    float* vh  = kh + n;
    float* kh0 = vh + n;
    float* vh0 = kh0 + n;
    float* wbuf = vh0 + n;                        // fp32 weight copies, 296193 floats
    int*   lvOf = (int*)(wbuf + 296193 + 3);
    int*   flag = lvOf + F;

    // fp32 weight-copy offsets within wbuf
    const int oWq = 0,       oWk = 16384,  oWv = 32768,  oWo = 49152;
    const int oW1 = 65536,   oB1 = 98304;
    const int oW2 = 98560,   oB2 = 164096;
    const int oW3 = 164352,  oB3 = 229888;
    const int oW4 = 230144,  oB4 = 295680;
    const int oW5 = 295936,  oB5 = 296192;
    const int wtot = 296193;

    WSegs segs = {{
        { d_in[1],  oWq, 16384 }, { d_in[2],  oWk, 16384 },
        { d_in[3],  oWv, 16384 }, { d_in[4],  oWo, 16384 },
        { d_in[5],  oW1, 32768 }, { d_in[6],  oB1, 256 },
        { d_in[7],  oW2, 65536 }, { d_in[8],  oB2, 256 },
        { d_in[9],  oW3, 65536 }, { d_in[10], oB3, 256 },
        { d_in[11], oW4, 65536 }, { d_in[12], oB4, 256 },
        { d_in[13], oW5, 256 },   { d_in[14], oB5, 1 },
    }};

    float* out0 = (float*)d_out;                  // final.transpose(0,2,1): [B,C,F] fp32
    float* out1 = out0 + (size_t)NB * C * F;      // scores: [B,F,1] fp32

    k_detect<<<1, 256, 0, stream>>>(d_in[0], flag);
    k_lvof<<<(F + 255) / 256, 256, 0, stream>>>(lvOf);
    k_convert<<<(wtot + 255) / 256, 256, 0, stream>>>(segs, flag, wbuf, wtot);
    k_transpose_in<<<dim3(F / 32, C / 32, NB), dim3(32, 8), 0, stream>>>(d_in[0], flag, cur);
    k_proj_init<<<(NB * F) / 8, 128, 0, stream>>>(cur, wbuf + oWq, wbuf + oWk, wbuf + oWv,
                                                  qh, kh, vh, kh0, vh0);

    int S = ((Bd + 3) / 4) * 4;                   // slots per mesh, mult of 4
    for (int lv = 0; lv < NLV; ++lv) {
        k_level<<<2 * S, 256, 0, stream>>>(lv, Bd, levels, lvOf, qh, cur, kh, vh, kh0, vh0,
                                           wbuf + oWk, wbuf + oWv, wbuf + oWo);
    }

    k_mlp<<<(NB * F) / 8, 256, 0, stream>>>(cur, wbuf + oW1, wbuf + oB1, wbuf + oW2, wbuf + oB2,
                                            wbuf + oW3, wbuf + oB3, wbuf + oW4, wbuf + oB4,
                                            wbuf + oW5, wbuf + oB5, out1);
    k_transpose_out<<<dim3(F / 32, C / 32, NB), dim3(32, 8), 0, stream>>>(cur, out0);
}

// Round 4
// 1976.156 us; speedup vs baseline: 2.0295x; 2.0295x over previous
//
#include <hip/hip_runtime.h>
#include <hip/hip_bf16.h>
#include <stdint.h>

#define GRIDN 48
#define F 2304
#define C 128
#define H 8
#define DH 16
#define NB 2          // batch (meshes)
#define WID 256
#define NLV 49        // BFS levels for GRID=48, anchor at (24,24)

typedef __hip_bfloat16 bf16;

__device__ __forceinline__ float b2f(bf16 v) { return __bfloat162float(v); }

// ---------------------------------------------------------------- K-1: input dtype detector
__global__ void k_detect(const void* __restrict__ x, int* __restrict__ flag) {
    __shared__ int bad;
    if (threadIdx.x == 0) bad = 0;
    __syncthreads();
    const bf16* xb = (const bf16*)x;
    int insane = 0;
    #pragma unroll
    for (int i = 0; i < 8; ++i) {
        float v = b2f(xb[threadIdx.x * 8 + i]);
        if (!(fabsf(v) < 1e10f)) insane = 1;   // catches NaN/Inf/huge
    }
    if (insane) atomicOr(&bad, 1);
    __syncthreads();
    if (threadIdx.x == 0) *flag = bad;
}

// ---------------------------------------------------------------- K0: BFS-ring permutation of the key axis
// permIdx[face] = position of face when keys are sorted by ring level. Ring lv
// occupies contiguous [ringStart[lv], ringStart[lv+1]) (host recomputes same).
__global__ void k_perm(int* __restrict__ permIdx) {
    __shared__ int cnt[NLV], start[NLV];
    int t = threadIdx.x;
    if (t < NLV) cnt[t] = 0;
    __syncthreads();
    for (int f = t; f < F; f += 256) {
        int d = abs(f / GRIDN - GRIDN / 2) + abs(f % GRIDN - GRIDN / 2);
        atomicAdd(&cnt[d], 1);
    }
    __syncthreads();
    if (t == 0) {
        int s = 0;
        for (int l = 0; l < NLV; ++l) { start[l] = s; s += cnt[l]; }
    }
    __syncthreads();
    for (int f = t; f < F; f += 256) {
        int d = abs(f / GRIDN - GRIDN / 2) + abs(f % GRIDN - GRIDN / 2);
        permIdx[f] = atomicAdd(&start[d], 1);
    }
}

// ---------------------------------------------------------------- K0b: convert all weights/biases to fp32
struct WSeg { const void* src; int off; int cnt; };
struct WSegs { WSeg s[14]; };

__global__ void k_convert(WSegs segs, const int* __restrict__ flag,
                          float* __restrict__ dst, int total) {
    int i = blockIdx.x * blockDim.x + threadIdx.x;
    if (i >= total) return;
    bool f32 = (*flag != 0);
    #pragma unroll 1
    for (int j = 0; j < 14; ++j) {
        int off = segs.s[j].off, cnt = segs.s[j].cnt;
        if (i >= off && i < off + cnt) {
            int k = i - off;
            dst[i] = f32 ? ((const float*)segs.s[j].src)[k]
                         : b2f(((const bf16*)segs.s[j].src)[k]);
            return;
        }
    }
}

// ---------------------------------------------------------------- K1: x[B,C,F] -> cur[B,F,C] f32
__global__ void k_transpose_in(const void* __restrict__ x, const int* __restrict__ flag,
                               float* __restrict__ cur) {
    __shared__ float tile[32][33];
    bool f32 = (*flag != 0);
    int b = blockIdx.z;
    int f0 = blockIdx.x * 32, c0 = blockIdx.y * 32;
    int tx = threadIdx.x, ty = threadIdx.y;            // 32 x 8
    #pragma unroll
    for (int i = 0; i < 4; ++i) {
        int c = c0 + ty + i * 8;
        size_t idx = ((size_t)b * C + c) * F + f0 + tx;
        tile[ty + i * 8][tx] = f32 ? ((const float*)x)[idx] : b2f(((const bf16*)x)[idx]);
    }
    __syncthreads();
    #pragma unroll
    for (int i = 0; i < 4; ++i) {
        int f = f0 + ty + i * 8;
        cur[((size_t)b * F + f) * C + c0 + tx] = tile[tx][ty + i * 8];
    }
}

// ---------------------------------------------------------------- K2: init projections.
// qh row-layout [mesh][F][C] (pre-scaled); khT/vhT transposed+permuted [mesh][c][F] column permIdx[face].
__global__ __launch_bounds__(128) void k_proj_init(
        const float* __restrict__ cur, const int* __restrict__ permIdx,
        const float* __restrict__ Wq, const float* __restrict__ Wk, const float* __restrict__ Wv,
        float* __restrict__ qh, float* __restrict__ khT, float* __restrict__ vhT) {
    __shared__ float rows[8][C];
    int r0 = blockIdx.x * 8;
    int tid = threadIdx.x;  // 0..127 = output channel
    #pragma unroll
    for (int r = 0; r < 8; ++r) rows[r][tid] = cur[(size_t)(r0 + r) * C + tid];
    __syncthreads();
    float aq[8], ak[8], av[8];
    #pragma unroll
    for (int r = 0; r < 8; ++r) { aq[r] = 0.f; ak[r] = 0.f; av[r] = 0.f; }
    for (int k = 0; k < C; ++k) {
        float wq = Wq[k * C + tid];
        float wk = Wk[k * C + tid];
        float wv = Wv[k * C + tid];
        #pragma unroll
        for (int r = 0; r < 8; ++r) {
            float xv = rows[r][k];
            aq[r] = fmaf(xv, wq, aq[r]);
            ak[r] = fmaf(xv, wk, ak[r]);
            av[r] = fmaf(xv, wv, av[r]);
        }
    }
    const float scale = 0.25f;  // 1/sqrt(DH)
    #pragma unroll
    for (int r = 0; r < 8; ++r) {
        int grow = r0 + r;
        int mesh = grow / F, face = grow % F;
        int p = permIdx[face];
        qh[(size_t)grow * C + tid] = aq[r] * scale;
        khT[((size_t)mesh * C + tid) * F + p] = ak[r];
        vhT[((size_t)mesh * C + tid) * F + p] = av[r];
    }
}

// ---------------------------------------------------------------- K2b: frozen copies khT0/vhT0
__global__ void k_copy(const float4* __restrict__ src, float4* __restrict__ dst, int n4) {
    int i = blockIdx.x * blockDim.x + threadIdx.x;
    if (i < n4) dst[i] = src[i];
}

// ---------------------------------------------------------------- K3: one BFS level, 2 queries per block
__global__ __launch_bounds__(256) void k_level(
        int lv, int Bd, int rs, int re,
        const int* __restrict__ levels, const int* __restrict__ permIdx,
        const float* __restrict__ qh_all, float* __restrict__ cur,
        float* __restrict__ khT, float* __restrict__ vhT,
        const float* __restrict__ khT0, const float* __restrict__ vhT0,
        const float* __restrict__ Wk, const float* __restrict__ Wv, const float* __restrict__ Wo) {
    int bx = blockIdx.x;
    int mesh = bx & 1;                 // parity swizzle: mesh per XCD-parity
    int spair = bx >> 1;
    int s0 = spair * 2, s1 = s0 + 1;
    int face0 = (s0 < Bd) ? levels[lv * Bd + s0] : F;
    int face1 = (s1 < Bd) ? levels[lv * Bd + s1] : F;
    bool a0 = (face0 >= 0 && face0 < F), a1 = (face1 >= 0 && face1 < F);
    if (!a0 && !a1) return;

    __shared__ float sQh[2][C], sQ[2][C], sRed[2][C], sNew[C];
    __shared__ float sL[2][H];
    int tid = threadIdx.x;
    size_t row0 = ((size_t)mesh * F + face0) * C;
    size_t row1 = ((size_t)mesh * F + face1) * C;
    if (tid < C) {
        if (a0) { sQ[0][tid] = cur[row0 + tid]; sQh[0][tid] = qh_all[row0 + tid]; }
        else    { sQ[0][tid] = 0.f; sQh[0][tid] = 0.f; }
    } else {
        int c = tid - C;
        if (a1) { sQ[1][c] = cur[row1 + c]; sQh[1][c] = qh_all[row1 + c]; }
        else    { sQ[1][c] = 0.f; sQh[1][c] = 0.f; }
    }
    __syncthreads();

    int head = tid >> 5, sub = tid & 31;
    float q0[DH], q1[DH];
    #pragma unroll
    for (int d = 0; d < DH; ++d) { q0[d] = sQh[0][head * DH + d]; q1[d] = sQh[1][head * DH + d]; }

    const float* Kb = khT  + ((size_t)mesh * C + head * DH) * F;
    const float* Vb = vhT  + ((size_t)mesh * C + head * DH) * F;
    const float* Kz = khT0 + ((size_t)mesh * C + head * DH) * F;
    const float* Vz = vhT0 + ((size_t)mesh * C + head * DH) * F;

    float m0 = -1e30f, l0 = 0.f, m1 = -1e30f, l1 = 0.f;
    float acc0[DH], acc1[DH];
    #pragma unroll
    for (int d = 0; d < DH; ++d) { acc0[d] = 0.f; acc1[d] = 0.f; }

    for (int base = 0; base < F; base += 128) {
        int p4 = base + 4 * sub;
        float sx0 = 0, sy0 = 0, sz0 = 0, sw0 = 0;
        float sx1 = 0, sy1 = 0, sz1 = 0, sw1 = 0;
        bool grp = (base < re) && (base + 128 > rs);    // block-uniform: stale interval overlap
        int t0 = 0, t1 = 0, t2 = 0, t3 = 0;
        if (!grp) {
            #pragma unroll
            for (int d = 0; d < DH; ++d) {
                float4 kk = *(const float4*)(Kb + d * F + p4);
                float a = q0[d], b = q1[d];
                sx0 = fmaf(a, kk.x, sx0); sy0 = fmaf(a, kk.y, sy0);
                sz0 = fmaf(a, kk.z, sz0); sw0 = fmaf(a, kk.w, sw0);
                sx1 = fmaf(b, kk.x, sx1); sy1 = fmaf(b, kk.y, sy1);
                sz1 = fmaf(b, kk.z, sz1); sw1 = fmaf(b, kk.w, sw1);
            }
        } else {
            t0 = (p4 >= rs && p4 < re); t1 = (p4 + 1 >= rs && p4 + 1 < re);
            t2 = (p4 + 2 >= rs && p4 + 2 < re); t3 = (p4 + 3 >= rs && p4 + 3 < re);
            #pragma unroll
            for (int d = 0; d < DH; ++d) {
                float4 kk = *(const float4*)(Kb + d * F + p4);
                float4 kz = *(const float4*)(Kz + d * F + p4);
                kk.x = t0 ? kz.x : kk.x; kk.y = t1 ? kz.y : kk.y;
                kk.z = t2 ? kz.z : kk.z; kk.w = t3 ? kz.w : kk.w;
                float a = q0[d], b = q1[d];
                sx0 = fmaf(a, kk.x, sx0); sy0 = fmaf(a, kk.y, sy0);
                sz0 = fmaf(a, kk.z, sz0); sw0 = fmaf(a, kk.w, sw0);
                sx1 = fmaf(b, kk.x, sx1); sy1 = fmaf(b, kk.y, sy1);
                sz1 = fmaf(b, kk.z, sz1); sw1 = fmaf(b, kk.w, sw1);
            }
        }
        // online softmax update, query 0
        float mx0 = fmaxf(fmaxf(sx0, sy0), fmaxf(sz0, sw0));
        float mn0 = fmaxf(m0, mx0);
        float c0 = __expf(m0 - mn0);
        float px0 = __expf(sx0 - mn0), py0 = __expf(sy0 - mn0);
        float pz0 = __expf(sz0 - mn0), pw0 = __expf(sw0 - mn0);
        l0 = fmaf(l0, c0, px0 + py0 + pz0 + pw0);
        m0 = mn0;
        // query 1
        float mx1 = fmaxf(fmaxf(sx1, sy1), fmaxf(sz1, sw1));
        float mn1 = fmaxf(m1, mx1);
        float c1e = __expf(m1 - mn1);
        float px1 = __expf(sx1 - mn1), py1 = __expf(sy1 - mn1);
        float pz1 = __expf(sz1 - mn1), pw1 = __expf(sw1 - mn1);
        l1 = fmaf(l1, c1e, px1 + py1 + pz1 + pw1);
        m1 = mn1;
        if (!grp) {
            #pragma unroll
            for (int d = 0; d < DH; ++d) {
                float4 vv = *(const float4*)(Vb + d * F + p4);
                float w0 = fmaf(px0, vv.x, fmaf(py0, vv.y, fmaf(pz0, vv.z, pw0 * vv.w)));
                float w1 = fmaf(px1, vv.x, fmaf(py1, vv.y, fmaf(pz1, vv.z, pw1 * vv.w)));
                acc0[d] = fmaf(acc0[d], c0, w0);
                acc1[d] = fmaf(acc1[d], c1e, w1);
            }
        } else {
            #pragma unroll
            for (int d = 0; d < DH; ++d) {
                float4 vv = *(const float4*)(Vb + d * F + p4);
                float4 vz = *(const float4*)(Vz + d * F + p4);
                vv.x = t0 ? vz.x : vv.x; vv.y = t1 ? vz.y : vv.y;
                vv.z = t2 ? vz.z : vv.z; vv.w = t3 ? vz.w : vv.w;
                float w0 = fmaf(px0, vv.x, fmaf(py0, vv.y, fmaf(pz0, vv.z, pw0 * vv.w)));
                float w1 = fmaf(px1, vv.x, fmaf(py1, vv.y, fmaf(pz1, vv.z, pw1 * vv.w)));
                acc0[d] = fmaf(acc0[d], c0, w0);
                acc1[d] = fmaf(acc1[d], c1e, w1);
            }
        }
    }

    // merge 32 per-lane online-softmax states per head
    #pragma unroll
    for (int w = 16; w >= 1; w >>= 1) {
        float mo = __shfl_xor(m0, w), lo = __shfl_xor(l0, w);
        float mn = fmaxf(m0, mo);
        float ca = __expf(m0 - mn), cb = __expf(mo - mn);
        l0 = l0 * ca + lo * cb;
        #pragma unroll
        for (int d = 0; d < DH; ++d) {
            float ao = __shfl_xor(acc0[d], w);
            acc0[d] = acc0[d] * ca + ao * cb;
        }
        m0 = mn;
        mo = __shfl_xor(m1, w); lo = __shfl_xor(l1, w);
        mn = fmaxf(m1, mo);
        ca = __expf(m1 - mn); cb = __expf(mo - mn);
        l1 = l1 * ca + lo * cb;
        #pragma unroll
        for (int d = 0; d < DH; ++d) {
            float ao = __shfl_xor(acc1[d], w);
            acc1[d] = acc1[d] * ca + ao * cb;
        }
        m1 = mn;
    }
    if (sub == 0) {
        sL[0][head] = l0; sL[1][head] = l1;
        #pragma unroll
        for (int d = 0; d < DH; ++d) {
            sRed[0][head * DH + d] = acc0[d];
            sRed[1][head * DH + d] = acc1[d];
        }
    }
    __syncthreads();
    if (tid < C) sRed[0][tid] = sRed[0][tid] / sL[0][tid >> 4];
    else { int c = tid - C; sRed[1][c] = sRed[1][c] / sL[1][c >> 4]; }
    __syncthreads();

    // epilogue per query: out-proj + resid, then K/V column refresh (ring-lv cols;
    // same-level readers take them from khT0/vhT0, so the eager write is race-free)
    #pragma unroll 1
    for (int j = 0; j < 2; ++j) {
        bool act = j == 0 ? a0 : a1;
        if (!act) continue;
        size_t rowj = j == 0 ? row0 : row1;
        int facej = j == 0 ? face0 : face1;
        if (tid < C) {
            float o = 0.f;
            for (int k = 0; k < C; ++k) o = fmaf(sRed[j][k], Wo[k * C + tid], o);
            float nv = sQ[j][tid] + o;
            sNew[tid] = nv;
            cur[rowj + tid] = nv;
        }
        __syncthreads();
        int p = permIdx[facej];
        if (tid < C) {
            float a = 0.f;
            for (int k = 0; k < C; ++k) a = fmaf(sNew[k], Wk[k * C + tid], a);
            khT[((size_t)mesh * C + tid) * F + p] = a;
        } else {
            int c = tid - C;
            float a = 0.f;
            for (int k = 0; k < C; ++k) a = fmaf(sNew[k], Wv[k * C + c], a);
            vhT[((size_t)mesh * C + c) * F + p] = a;
        }
        __syncthreads();
    }
}

// ---------------------------------------------------------------- K4: 5-layer MLP + sigmoid (8 rows/block)
__global__ __launch_bounds__(256) void k_mlp(
        const float* __restrict__ cur,
        const float* __restrict__ W1, const float* __restrict__ b1,
        const float* __restrict__ W2, const float* __restrict__ b2,
        const float* __restrict__ W3, const float* __restrict__ b3,
        const float* __restrict__ W4, const float* __restrict__ b4,
        const float* __restrict__ W5, const float* __restrict__ b5,
        float* __restrict__ out_scores) {
    __shared__ float sIn[8][C];
    __shared__ float sA[8][WID];
    __shared__ float sB[8][WID];
    int tid = threadIdx.x;                        // 0..255
    int r0 = blockIdx.x * 8;
    for (int i = tid; i < 8 * C; i += 256) sIn[i >> 7][i & 127] = cur[(size_t)r0 * C + i];
    __syncthreads();
    {
        float a[8];
        #pragma unroll
        for (int r = 0; r < 8; ++r) a[r] = 0.f;
        for (int k = 0; k < C; ++k) {
            float w = W1[k * WID + tid];
            #pragma unroll
            for (int r = 0; r < 8; ++r) a[r] = fmaf(sIn[r][k], w, a[r]);
        }
        float bias = b1[tid];
        #pragma unroll
        for (int r = 0; r < 8; ++r) sA[r][tid] = fmaxf(a[r] + bias, 0.f);
    }
    __syncthreads();
    {
        float a[8];
        #pragma unroll
        for (int r = 0; r < 8; ++r) a[r] = 0.f;
        for (int k = 0; k < WID; ++k) {
            float w = W2[k * WID + tid];
            #pragma unroll
            for (int r = 0; r < 8; ++r) a[r] = fmaf(sA[r][k], w, a[r]);
        }
        float bias = b2[tid];
        #pragma unroll
        for (int r = 0; r < 8; ++r) sB[r][tid] = fmaxf(a[r] + bias, 0.f);
    }
    __syncthreads();
    {
        float a[8];
        #pragma unroll
        for (int r = 0; r < 8; ++r) a[r] = 0.f;
        for (int k = 0; k < WID; ++k) {
            float w = W3[k * WID + tid];
            #pragma unroll
            for (int r = 0; r < 8; ++r) a[r] = fmaf(sB[r][k], w, a[r]);
        }
        float bias = b3[tid];
        #pragma unroll
        for (int r = 0; r < 8; ++r) sA[r][tid] = fmaxf(a[r] + bias, 0.f);
    }
    __syncthreads();
    {
        float a[8];
        #pragma unroll
        for (int r = 0; r < 8; ++r) a[r] = 0.f;
        for (int k = 0; k < WID; ++k) {
            float w = W4[k * WID + tid];
            #pragma unroll
            for (int r = 0; r < 8; ++r) a[r] = fmaf(sA[r][k], w, a[r]);
        }
        float bias = b4[tid];
        #pragma unroll
        for (int r = 0; r < 8; ++r) sB[r][tid] = fmaxf(a[r] + bias, 0.f);
    }
    __syncthreads();
    if (tid < 8) {
        float a = b5[0];
        for (int k = 0; k < WID; ++k) a = fmaf(sB[tid][k], W5[k], a);
        out_scores[r0 + tid] = 1.f / (1.f + __expf(-a));
    }
}

// ---------------------------------------------------------------- K5: cur[B,F,C] f32 -> out0[B,C,F] f32
__global__ void k_transpose_out(const float* __restrict__ cur, float* __restrict__ out) {
    __shared__ float tile[32][33];
    int b = blockIdx.z;
    int f0 = blockIdx.x * 32, c0 = blockIdx.y * 32;
    int tx = threadIdx.x, ty = threadIdx.y;
    #pragma unroll
    for (int i = 0; i < 4; ++i) {
        int f = f0 + ty + i * 8;
        tile[ty + i * 8][tx] = cur[((size_t)b * F + f) * C + c0 + tx];
    }
    __syncthreads();
    #pragma unroll
    for (int i = 0; i < 4; ++i) {
        int c = c0 + ty + i * 8;
        out[((size_t)b * C + c) * F + f0 + tx] = tile[tx][ty + i * 8];
    }
}

// ----------------------------------------------------------------
extern "C" void kernel_launch(void* const* d_in, const int* in_sizes, int n_in,
                              void* d_out, int out_size, void* d_ws, size_t ws_size,
                              hipStream_t stream) {
    const int* levels = (const int*)d_in[15];
    int Bd = in_sizes[15] / NLV;                  // ring capacity per level

    const size_t n = (size_t)NB * F * C;          // 589824
    float* cur  = (float*)d_ws;
    float* qh   = cur + n;
    float* khT  = qh + n;
    float* vhT  = khT + n;
    float* khT0 = vhT + n;                        // khT0/vhT0 contiguous after khT/vhT
    float* vhT0 = khT0 + n;
    float* wbuf = vhT0 + n;                       // fp32 weight copies, 296193 floats
    int*   permIdx = (int*)(wbuf + 296193 + 3);
    int*   flag = permIdx + F;

    const int oWq = 0,       oWk = 16384,  oWv = 32768,  oWo = 49152;
    const int oW1 = 65536,   oB1 = 98304;
    const int oW2 = 98560,   oB2 = 164096;
    const int oW3 = 164352,  oB3 = 229888;
    const int oW4 = 230144,  oB4 = 295680;
    const int oW5 = 295936,  oB5 = 296192;
    const int wtot = 296193;

    WSegs segs = {{
        { d_in[1],  oWq, 16384 }, { d_in[2],  oWk, 16384 },
        { d_in[3],  oWv, 16384 }, { d_in[4],  oWo, 16384 },
        { d_in[5],  oW1, 32768 }, { d_in[6],  oB1, 256 },
        { d_in[7],  oW2, 65536 }, { d_in[8],  oB2, 256 },
        { d_in[9],  oW3, 65536 }, { d_in[10], oB3, 256 },
        { d_in[11], oW4, 65536 }, { d_in[12], oB4, 256 },
        { d_in[13], oW5, 256 },   { d_in[14], oB5, 1 },
    }};

    // host-side ring prefix (pure function of GRIDN; matches k_perm's device result)
    int ringStart[NLV + 1];
    {
        int cnt[NLV];
        for (int l = 0; l < NLV; ++l) cnt[l] = 0;
        for (int i = 0; i < GRIDN; ++i)
            for (int j = 0; j < GRIDN; ++j)
                cnt[(i < 24 ? 24 - i : i - 24) + (j < 24 ? 24 - j : j - 24)]++;
        ringStart[0] = 0;
        for (int l = 0; l < NLV; ++l) ringStart[l + 1] = ringStart[l] + cnt[l];
    }

    float* out0 = (float*)d_out;                  // final.transpose(0,2,1): [B,C,F] fp32
    float* out1 = out0 + (size_t)NB * C * F;      // scores: [B,F,1] fp32

    k_detect<<<1, 256, 0, stream>>>(d_in[0], flag);
    k_perm<<<1, 256, 0, stream>>>(permIdx);
    k_convert<<<(wtot + 255) / 256, 256, 0, stream>>>(segs, flag, wbuf, wtot);
    k_transpose_in<<<dim3(F / 32, C / 32, NB), dim3(32, 8), 0, stream>>>(d_in[0], flag, cur);
    k_proj_init<<<(NB * F) / 8, 128, 0, stream>>>(cur, permIdx, wbuf + oWq, wbuf + oWk, wbuf + oWv,
                                                  qh, khT, vhT);
    k_copy<<<(int)(2 * n / 4 + 255) / 256, 256, 0, stream>>>((const float4*)khT, (float4*)khT0,
                                                             (int)(2 * n / 4));

    for (int lv = 0; lv < NLV; ++lv) {
        int rs = ringStart[lv], re = ringStart[lv + 1];
        int ring = re - rs;
        int nspair = (ring + 1) / 2;
        k_level<<<2 * nspair, 256, 0, stream>>>(lv, Bd, rs, re, levels, permIdx, qh, cur,
                                                khT, vhT, khT0, vhT0,
                                                wbuf + oWk, wbuf + oWv, wbuf + oWo);
    }

    k_mlp<<<(NB * F) / 8, 256, 0, stream>>>(cur, wbuf + oW1, wbuf + oB1, wbuf + oW2, wbuf + oB2,
                                            wbuf + oW3, wbuf + oB3, wbuf + oW4, wbuf + oB4,
                                            wbuf + oW5, wbuf + oB5, out1);
    k_transpose_out<<<dim3(F / 32, C / 32, NB), dim3(32, 8), 0, stream>>>(cur, out0);
}